// Round 6
// baseline (637.101 us; speedup 1.0000x reference)
//
#include <hip/hip_runtime.h>

#define NUM_TAGS 128
#define NUM_FEATS 500000
#define BB 64
#define TT 512
#define FF 8

#define SWT_BYTES 256000000ull            // 500000*128*4
#define EM_BYTES  16777216ull             // 64*512*128*4
#define NEED_FULL (SWT_BYTES + EM_BYTES)

typedef float f2 __attribute__((ext_vector_type(2)));

// Raw workgroup barrier: wait LDS ops only (no vmcnt drain), so the 4-deep
// ev prefetch stays in flight across steps. sched_barrier(0) AFTER s_barrier
// keeps next-step ds_reads from hoisting above the barrier (m152-class race).
__device__ __forceinline__ void barrier_lds() {
  asm volatile("s_waitcnt lgkmcnt(0)" ::: "memory");
  __builtin_amdgcn_s_barrier();
  __builtin_amdgcn_sched_barrier(0);
}

// T1: transpose state_weights [128][500000] -> swT [500000][128]. (round-0, proven)
__global__ __launch_bounds__(256) void transpose_kernel(
    const float* __restrict__ sw, float* __restrict__ swT) {
  __shared__ float tile[32][129];
  const int f0 = blockIdx.x * 32;
  const int t = threadIdx.x;
  const int fi = t & 31, kb = t >> 5;          // kb 0..7
#pragma unroll
  for (int it = 0; it < 16; ++it) {
    int k = kb + it * 8;
    tile[fi][k] = sw[(size_t)k * NUM_FEATS + f0 + fi];  // 128B coalesced
  }
  __syncthreads();
  const int k2 = t & 127, fo = t >> 7;         // fo 0..1
#pragma unroll
  for (int it = 0; it < 16; ++it) {
    int f2i = fo + it * 2;
    swT[(size_t)(f0 + f2i) * NUM_TAGS + k2] = tile[f2i][k2];  // 512B coalesced
  }
}

// K1a: emissions from transposed table; exp() folded. (round-0, proven)
__global__ __launch_bounds__(128) void gather_t_kernel(
    const int* __restrict__ feats, const float* __restrict__ swT,
    float* __restrict__ em_exp) {
  const int token = blockIdx.x;
  const int k = threadIdx.x;
  const int* f = feats + token * FF;
  float s = 0.f;
#pragma unroll
  for (int i = 0; i < FF; ++i) s += swT[(size_t)f[i] * NUM_TAGS + k];
  em_exp[(size_t)token * NUM_TAGS + k] = __expf(s);
}

// K1b fallback: direct strided gather. (round-0, proven)
__global__ __launch_bounds__(128) void gather_f_kernel(
    const int* __restrict__ feats, const float* __restrict__ sw,
    float* __restrict__ em_exp) {
  const int token = blockIdx.x;
  const int k = threadIdx.x;
  const int* f = feats + token * FF;
  const float* row = sw + (size_t)k * NUM_FEATS;
  float s = 0.f;
#pragma unroll
  for (int i = 0; i < FF; ++i) s += row[f[i]];
  em_exp[(size_t)token * NUM_TAGS + k] = __expf(s);
}

// One forward step, 2-wave version: thread j computes the FULL 128-term dot for
// column j (64 pk-FMA), stride-1 alpha write, broadcast b128 alpha reads.
// No cross-lane reduce at all; ONE 2-wave lgkm-only barrier per step.
__device__ __forceinline__ void stepw(float& evreg, int t,
                                      const float* __restrict__ embx, int j,
                                      const float* alf_src, float* alf_dst,
                                      const f2 (&eT2)[64]) {
  float ev = evreg;
  int tp = t + 4; if (tp > TT - 1) tp = TT - 1;        // clamp (redundant reload ok)
  evreg = embx[tp * NUM_TAGS + j];                     // prefetch 4 steps ahead
  const float4* a4 = (const float4*)alf_src;           // wave-uniform: broadcast
  f2 acc0 = {0.f, 0.f}, acc1 = {0.f, 0.f}, acc2 = {0.f, 0.f}, acc3 = {0.f, 0.f};
#pragma unroll
  for (int i = 0; i < 8; ++i) {
    float4 a = a4[4 * i + 0], b = a4[4 * i + 1];
    float4 c = a4[4 * i + 2], d = a4[4 * i + 3];
    acc0 += (f2){a.x, a.y} * eT2[8 * i + 0];
    acc1 += (f2){a.z, a.w} * eT2[8 * i + 1];
    acc2 += (f2){b.x, b.y} * eT2[8 * i + 2];
    acc3 += (f2){b.z, b.w} * eT2[8 * i + 3];
    acc0 += (f2){c.x, c.y} * eT2[8 * i + 4];
    acc1 += (f2){c.z, c.w} * eT2[8 * i + 5];
    acc2 += (f2){d.x, d.y} * eT2[8 * i + 6];
    acc3 += (f2){d.z, d.w} * eT2[8 * i + 7];
  }
  f2 sA = acc0 + acc1, sB = acc2 + acc3;
  f2 sC = sA + sB;
  alf_dst[j] = (sC.x + sC.y) * ev * 0.0078125f;        // * 2^-7 rescale
  barrier_lds();
}

// K2: prob-space forward. 128 threads (2 waves), thread j owns column j.
// expT column j in 64 f2 VGPRs. 1 barrier/step, 0 bank conflicts, no shuffles.
__global__ __launch_bounds__(128, 1) void fwd_kernel(
    const float* __restrict__ em_exp, const int* __restrict__ tags,
    const float* __restrict__ trans, const float* __restrict__ startT,
    const float* __restrict__ endT, float* __restrict__ out) {
  const int b = blockIdx.x;
  const int j = threadIdx.x;                           // 0..127

  __shared__ __align__(16) float alf[2][NUM_TAGS];     // double-buffered alpha
  __shared__ float sred[4];

  f2 eT2[64];                                          // expT column j (rows 0..127)
#pragma unroll
  for (int m = 0; m < 64; ++m) {
    eT2[m].x = __expf(trans[(2 * m) * NUM_TAGS + j]);
    eT2[m].y = __expf(trans[(2 * m + 1) * NUM_TAGS + j]);
  }

  const float* embx = em_exp + (size_t)b * TT * NUM_TAGS;

  alf[0][j] = __expf(startT[j]) * embx[j];
  float evA = embx[1 * NUM_TAGS + j], evB = embx[2 * NUM_TAGS + j],
        evC = embx[3 * NUM_TAGS + j], evD = embx[4 * NUM_TAGS + j];
  __syncthreads();

  int cur = 0;
  for (int t = 1; t + 3 < TT; t += 4) {                // t = 1..505, steps t..t+3
    stepw(evA, t + 0, embx, j, alf[cur], alf[cur ^ 1], eT2); cur ^= 1;
    stepw(evB, t + 1, embx, j, alf[cur], alf[cur ^ 1], eT2); cur ^= 1;
    stepw(evC, t + 2, embx, j, alf[cur], alf[cur ^ 1], eT2); cur ^= 1;
    stepw(evD, t + 3, embx, j, alf[cur], alf[cur ^ 1], eT2); cur ^= 1;
  }
  stepw(evA, 509, embx, j, alf[cur], alf[cur ^ 1], eT2); cur ^= 1;
  stepw(evB, 510, embx, j, alf[cur], alf[cur ^ 1], eT2); cur ^= 1;
  stepw(evC, 511, embx, j, alf[cur], alf[cur ^ 1], eT2); cur ^= 1;

  // logZ: reduce alf[cur][j] * exp(end[j]) over 128 threads (2 waves)
  float val = alf[cur][j] * __expf(endT[j]);
#pragma unroll
  for (int off = 32; off > 0; off >>= 1) val += __shfl_down(val, off, 64);
  if ((j & 63) == 0) sred[j >> 6] = val;

  // gold: thread j handles t = j, j+128, j+256, j+384
  const int* tb = tags + b * TT;
  float g = 0.f;
#pragma unroll
  for (int p = 0; p < 4; ++p) {
    int t = j + 128 * p;
    int tg = tb[t];
    g += __logf(embx[t * NUM_TAGS + tg]);
    if (t < TT - 1) g += trans[tg * NUM_TAGS + tb[t + 1]];
  }
  if (j == 0) g += startT[tb[0]] + endT[tb[TT - 1]];
#pragma unroll
  for (int off = 32; off > 0; off >>= 1) g += __shfl_down(g, off, 64);
  if ((j & 63) == 0) sred[2 + (j >> 6)] = g;
  __syncthreads();

  if (j == 0) {
    float logz = __logf(sred[0] + sred[1]) + 511.0f * 7.0f * 0.69314718055994531f;
    out[b] = logz - (sred[2] + sred[3]);
  }
}

extern "C" void kernel_launch(void* const* d_in, const int* in_sizes, int n_in,
                              void* d_out, int out_size, void* d_ws, size_t ws_size,
                              hipStream_t stream) {
  const int* feats = (const int*)d_in[0];
  const int* tags = (const int*)d_in[1];
  const float* sw = (const float*)d_in[2];
  const float* trans = (const float*)d_in[3];
  const float* startT = (const float*)d_in[4];
  const float* endT = (const float*)d_in[5];
  float* out = (float*)d_out;

  if (ws_size >= NEED_FULL) {
    float* swT = (float*)d_ws;
    float* em_exp = (float*)((char*)d_ws + SWT_BYTES);
    transpose_kernel<<<NUM_FEATS / 32, 256, 0, stream>>>(sw, swT);
    gather_t_kernel<<<BB * TT, 128, 0, stream>>>(feats, swT, em_exp);
    fwd_kernel<<<BB, 128, 0, stream>>>(em_exp, tags, trans, startT, endT, out);
  } else {
    float* em_exp = (float*)d_ws;
    gather_f_kernel<<<BB * TT, 128, 0, stream>>>(feats, sw, em_exp);
    fwd_kernel<<<BB, 128, 0, stream>>>(em_exp, tags, trans, startT, endT, out);
  }
}

// Round 7
// 538.768 us; speedup vs baseline: 1.1825x; 1.1825x over previous
//
#include <hip/hip_runtime.h>

#define NUM_TAGS 128
#define NUM_FEATS 500000
#define BB 64
#define TT 512
#define FF 8

#define SWT_BYTES 256000000ull            // 500000*128*4
#define EM_BYTES  16777216ull             // 64*512*128*4
#define NEED_FULL (SWT_BYTES + EM_BYTES)

typedef float f2 __attribute__((ext_vector_type(2)));

// Padded alpha index: quarter g>>5 stored at stride 36 floats (144 B, 16B-aligned)
// -> the 4 per-quarter broadcast groups of a ds_read_b128 hit disjoint banks.
#define AP(j) ((((j) >> 5) * 36) + ((j) & 31))

// Raw workgroup barrier: wait LDS ops only (no vmcnt drain), so the 4-deep
// ev prefetch stays in flight across steps. sched_barrier(0) AFTER s_barrier
// keeps next-step ds_reads from hoisting above the barrier (m152-class race).
__device__ __forceinline__ void barrier_lds() {
  asm volatile("s_waitcnt lgkmcnt(0)" ::: "memory");
  __builtin_amdgcn_s_barrier();
  __builtin_amdgcn_sched_barrier(0);
}

// Quad butterfly sum via DPP (VALU pipe) — lanes 4j..4j+3 end with the 4-lane sum.
__device__ __forceinline__ float quad_sum_dpp(float r) {
  int t1 = __builtin_amdgcn_mov_dpp(__builtin_bit_cast(int, r), 0xB1, 0xF, 0xF, true);
  r += __builtin_bit_cast(float, t1);                  // quad_perm [1,0,3,2]: xor 1
  int t2 = __builtin_amdgcn_mov_dpp(__builtin_bit_cast(int, r), 0x4E, 0xF, 0xF, true);
  r += __builtin_bit_cast(float, t2);                  // quad_perm [2,3,0,1]: xor 2
  return r;
}

// T1: transpose state_weights [128][500000] -> swT [500000][128]. (round-0, proven)
__global__ __launch_bounds__(256) void transpose_kernel(
    const float* __restrict__ sw, float* __restrict__ swT) {
  __shared__ float tile[32][129];
  const int f0 = blockIdx.x * 32;
  const int t = threadIdx.x;
  const int fi = t & 31, kb = t >> 5;          // kb 0..7
#pragma unroll
  for (int it = 0; it < 16; ++it) {
    int k = kb + it * 8;
    tile[fi][k] = sw[(size_t)k * NUM_FEATS + f0 + fi];  // 128B coalesced
  }
  __syncthreads();
  const int k2 = t & 127, fo = t >> 7;         // fo 0..1
#pragma unroll
  for (int it = 0; it < 16; ++it) {
    int f2i = fo + it * 2;
    swT[(size_t)(f0 + f2i) * NUM_TAGS + k2] = tile[f2i][k2];  // 512B coalesced
  }
}

// K1a: emissions from transposed table; exp() folded. (round-0, proven)
__global__ __launch_bounds__(128) void gather_t_kernel(
    const int* __restrict__ feats, const float* __restrict__ swT,
    float* __restrict__ em_exp) {
  const int token = blockIdx.x;
  const int k = threadIdx.x;
  const int* f = feats + token * FF;
  float s = 0.f;
#pragma unroll
  for (int i = 0; i < FF; ++i) s += swT[(size_t)f[i] * NUM_TAGS + k];
  em_exp[(size_t)token * NUM_TAGS + k] = __expf(s);
}

// K1b fallback: direct strided gather. (round-0, proven)
__global__ __launch_bounds__(128) void gather_f_kernel(
    const int* __restrict__ feats, const float* __restrict__ sw,
    float* __restrict__ em_exp) {
  const int token = blockIdx.x;
  const int k = threadIdx.x;
  const int* f = feats + token * FF;
  const float* row = sw + (size_t)k * NUM_FEATS;
  float s = 0.f;
#pragma unroll
  for (int i = 0; i < FF; ++i) s += row[f[i]];
  em_exp[(size_t)token * NUM_TAGS + k] = __expf(s);
}

// expT pair (rows 32q+2I, 32q+2I+1; column j) — init for named SSA registers.
#define EINIT(I) (f2){__expf(trans[(32 * q + 2 * (I)) * NUM_TAGS + j]), \
                      __expf(trans[(32 * q + 2 * (I) + 1) * NUM_TAGS + j])}

// One forward step. All expT state in NAMED f2 SSA values (e00..e15) so the
// "memory" clobber in barrier_lds cannot force scratch reloads (R6 post-mortem:
// array form was alloca'd -> per-step scratch traffic, VGPR_Count 32/84).
#define STEP(EV, T, SRC, DST) do {                                          \
  float ev_ = (EV);                                                         \
  int tp_ = (T) + 4; if (tp_ > TT - 1) tp_ = TT - 1;                        \
  (EV) = embx[tp_ * NUM_TAGS + j];               /* prefetch 4 ahead */     \
  const float4* a4_ = (const float4*)((SRC) + q * 36);                      \
  float4 A0 = a4_[0], A1 = a4_[1], A2 = a4_[2], A3 = a4_[3];                \
  float4 A4 = a4_[4], A5 = a4_[5], A6 = a4_[6], A7 = a4_[7];                \
  f2 ac0 = {0.f, 0.f}, ac1 = {0.f, 0.f};                                    \
  ac0 += (f2){A0.x, A0.y} * e00;  ac1 += (f2){A0.z, A0.w} * e01;            \
  ac0 += (f2){A1.x, A1.y} * e02;  ac1 += (f2){A1.z, A1.w} * e03;            \
  ac0 += (f2){A2.x, A2.y} * e04;  ac1 += (f2){A2.z, A2.w} * e05;            \
  ac0 += (f2){A3.x, A3.y} * e06;  ac1 += (f2){A3.z, A3.w} * e07;            \
  ac0 += (f2){A4.x, A4.y} * e08;  ac1 += (f2){A4.z, A4.w} * e09;            \
  ac0 += (f2){A5.x, A5.y} * e10;  ac1 += (f2){A5.z, A5.w} * e11;            \
  ac0 += (f2){A6.x, A6.y} * e12;  ac1 += (f2){A6.z, A6.w} * e13;            \
  ac0 += (f2){A7.x, A7.y} * e14;  ac1 += (f2){A7.z, A7.w} * e15;            \
  f2 s_ = ac0 + ac1;                                                        \
  float r_ = quad_sum_dpp(s_.x + s_.y);                                     \
  if (q == 0) (DST)[AP(j)] = r_ * ev_ * 0.0078125f;  /* * 2^-7 rescale */   \
  barrier_lds();                                                            \
} while (0)

// K2: prob-space forward. 512 threads, j=tid>>2 owns output column, q=tid&3 the
// sum quarter (32 FMAs). expT slice in 16 named f2 regs. 1 barrier/step.
__global__ __launch_bounds__(512, 1) void fwd_kernel(
    const float* __restrict__ em_exp, const int* __restrict__ tags,
    const float* __restrict__ trans, const float* __restrict__ startT,
    const float* __restrict__ endT, float* __restrict__ out) {
  const int b = blockIdx.x;
  const int tid = threadIdx.x;
  const int j = tid >> 2, q = tid & 3;

  __shared__ __align__(16) float alf[2][144];          // double-buffered, padded
  __shared__ float sred[16];

  f2 e00 = EINIT(0),  e01 = EINIT(1),  e02 = EINIT(2),  e03 = EINIT(3);
  f2 e04 = EINIT(4),  e05 = EINIT(5),  e06 = EINIT(6),  e07 = EINIT(7);
  f2 e08 = EINIT(8),  e09 = EINIT(9),  e10 = EINIT(10), e11 = EINIT(11);
  f2 e12 = EINIT(12), e13 = EINIT(13), e14 = EINIT(14), e15 = EINIT(15);

  const float* embx = em_exp + (size_t)b * TT * NUM_TAGS;

  if (q == 0) alf[0][AP(j)] = __expf(startT[j]) * embx[j];

  float evA = embx[1 * NUM_TAGS + j], evB = embx[2 * NUM_TAGS + j],
        evC = embx[3 * NUM_TAGS + j], evD = embx[4 * NUM_TAGS + j];
  __syncthreads();

  int cur = 0;
  for (int t = 1; t + 3 < TT; t += 4) {                // t = 1..505, steps t..t+3
    STEP(evA, t + 0, alf[cur], alf[cur ^ 1]); cur ^= 1;
    STEP(evB, t + 1, alf[cur], alf[cur ^ 1]); cur ^= 1;
    STEP(evC, t + 2, alf[cur], alf[cur ^ 1]); cur ^= 1;
    STEP(evD, t + 3, alf[cur], alf[cur ^ 1]); cur ^= 1;
  }
  STEP(evA, 509, alf[cur], alf[cur ^ 1]); cur ^= 1;
  STEP(evB, 510, alf[cur], alf[cur ^ 1]); cur ^= 1;
  STEP(evC, 511, alf[cur], alf[cur ^ 1]); cur ^= 1;

  // logZ: threads 0..127 (waves 0-1), reduce alpha * exp(end)
  if (tid < 128) {
    float val = alf[cur][AP(tid)] * __expf(endT[tid]);
#pragma unroll
    for (int off = 32; off > 0; off >>= 1) val += __shfl_down(val, off, 64);
    if ((tid & 63) == 0) sred[tid >> 6] = val;
  }

  // gold: thread tid handles t = tid
  const int* tb = tags + b * TT;
  const int t = tid;
  const int tg = tb[t];
  float g = __logf(embx[t * NUM_TAGS + tg]);
  if (t < TT - 1) g += trans[tg * NUM_TAGS + tb[t + 1]];
  if (t == 0) g += startT[tb[0]] + endT[tb[TT - 1]];
#pragma unroll
  for (int off = 32; off > 0; off >>= 1) g += __shfl_down(g, off, 64);
  if ((tid & 63) == 0) sred[8 + (tid >> 6)] = g;
  __syncthreads();

  if (tid == 0) {
    float logz = __logf(sred[0] + sred[1]) + 511.0f * 7.0f * 0.69314718055994531f;
    float gs = 0.f;
#pragma unroll
    for (int i = 0; i < 8; ++i) gs += sred[8 + i];
    out[b] = logz - gs;
  }
}

extern "C" void kernel_launch(void* const* d_in, const int* in_sizes, int n_in,
                              void* d_out, int out_size, void* d_ws, size_t ws_size,
                              hipStream_t stream) {
  const int* feats = (const int*)d_in[0];
  const int* tags = (const int*)d_in[1];
  const float* sw = (const float*)d_in[2];
  const float* trans = (const float*)d_in[3];
  const float* startT = (const float*)d_in[4];
  const float* endT = (const float*)d_in[5];
  float* out = (float*)d_out;

  if (ws_size >= NEED_FULL) {
    float* swT = (float*)d_ws;
    float* em_exp = (float*)((char*)d_ws + SWT_BYTES);
    transpose_kernel<<<NUM_FEATS / 32, 256, 0, stream>>>(sw, swT);
    gather_t_kernel<<<BB * TT, 128, 0, stream>>>(feats, swT, em_exp);
    fwd_kernel<<<BB, 512, 0, stream>>>(em_exp, tags, trans, startT, endT, out);
  } else {
    float* em_exp = (float*)d_ws;
    gather_f_kernel<<<BB * TT, 128, 0, stream>>>(feats, sw, em_exp);
    fwd_kernel<<<BB, 512, 0, stream>>>(em_exp, tags, trans, startT, endT, out);
  }
}